// Round 1
// baseline (2827.135 us; speedup 1.0000x reference)
//
#include <hip/hip_runtime.h>

#define VV 32000
#define EE 256
#define HH 512
#define BB 32
#define SS 80
#define TT 80
// decoder rows = B*(T-1) = 2528, padded to 2560 (20 tiles of 128)

typedef __attribute__((ext_vector_type(8))) _Float16 half8;
typedef __attribute__((ext_vector_type(4))) _Float16 half4;
typedef __attribute__((ext_vector_type(4))) float floatx4;

__device__ __forceinline__ void gload16(const _Float16* g, _Float16* l) {
  // async global->LDS, 16B per lane; LDS dest is wave-uniform base + lane*16
  __builtin_amdgcn_global_load_lds((const __attribute__((address_space(1))) void*)g,
                                   (__attribute__((address_space(3))) void*)l, 16, 0, 0);
}

// ---------------- embedding gather (fp32 -> fp16 rows) ----------------
__global__ __launch_bounds__(256) void embed_gather(
    const int* __restrict__ src, const int* __restrict__ tgt,
    const float* __restrict__ emb,
    _Float16* __restrict__ xsrc, _Float16* __restrict__ xdec)
{
  const int r = blockIdx.x;
  const int e = threadIdx.x; // EE == 256
  if (r < 2560) {
    const int tok = src[r];                       // r = b*80+s
    xsrc[(size_t)r*EE + e] = (_Float16)emb[(size_t)tok*EE + e];
  } else {
    const int rr = r - 2560;
    if (rr < 2528) {
      const int b = rr / 79, t = rr - b*79;
      const int tok = tgt[b*TT + t];
      xdec[(size_t)rr*EE + e] = (_Float16)emb[(size_t)tok*EE + e];
    } else {
      xdec[(size_t)rr*EE + e] = (_Float16)0.f;    // pad rows 2528..2559
    }
  }
}

// ---------------- weight fp32 -> fp16 conversion ----------------
__global__ __launch_bounds__(256) void wconv(
    const float* __restrict__ we, const float* __restrict__ wd, const float* __restrict__ ow,
    _Float16* __restrict__ weh, _Float16* __restrict__ wdh, _Float16* __restrict__ owh)
{
  const long n1 = 1536L*256;
  const long total = 2*n1 + (long)VV*1024;
  for (long i = (long)blockIdx.x*256 + threadIdx.x; i < total; i += (long)gridDim.x*256) {
    if (i < n1)           weh[i]        = (_Float16)we[i];
    else if (i < 2*n1)    wdh[i-n1]     = (_Float16)wd[i-n1];
    else                  owh[i-2*n1]   = (_Float16)ow[i-2*n1];
  }
}

// ---------------- generic fp16 MFMA GEMM: C(MxN) = A(MxK) * B(NxK)^T + bias ----
// MODE 0: C[row*ldc+col].  MODE 1: seq2seq logits scatter (skip rows>=2528).
template<int MODE>
__global__ __launch_bounds__(256) void mfma_gemm(
    const _Float16* __restrict__ A, int lda,
    const _Float16* __restrict__ Bm, int ldb,
    const float* __restrict__ bias,
    float* __restrict__ Cout, int ldc, int K)
{
  __shared__ _Float16 As[4096];  // 128 x 32
  __shared__ _Float16 Bs[4096];  // 128 x 32
  const int tid = threadIdx.x;
  const int lane = tid & 63;
  const int wv = tid >> 6;
  const int wr = wv >> 1, wc = wv & 1;
  const int mt = blockIdx.y, nt = blockIdx.x;
  floatx4 acc[4][4];
#pragma unroll
  for (int i=0;i<4;++i)
#pragma unroll
    for (int j=0;j<4;++j) acc[i][j] = (floatx4){0.f,0.f,0.f,0.f};
  const int srow = lane >> 2;
  const int scol = (lane & 3) * 8;
  const _Float16* Ab = A + (size_t)(mt*128)*lda;
  const _Float16* Bb = Bm + (size_t)(nt*128)*ldb;
  const int g8 = (lane >> 4) * 8;
  const int lr = lane & 15;
  for (int kb = 0; kb < K; kb += 32) {
    __syncthreads();   // protect LDS from prior iteration's readers
#pragma unroll
    for (int cc = 0; cc < 2; ++cc) {
      const int c = wv*2 + cc;   // 8 chunks of 1KB per 8KB tile
      gload16(Ab + (size_t)(c*16 + srow)*lda + kb + scol, As + c*512);
      gload16(Bb + (size_t)(c*16 + srow)*ldb + kb + scol, Bs + c*512);
    }
    __syncthreads();   // compiler drains vmcnt before barrier
    half8 af[4], bf[4];
#pragma unroll
    for (int i=0;i<4;++i) af[i] = *(const half8*)(As + (wr*64 + i*16 + lr)*32 + g8);
#pragma unroll
    for (int j=0;j<4;++j) bf[j] = *(const half8*)(Bs + (wc*64 + j*16 + lr)*32 + g8);
#pragma unroll
    for (int i=0;i<4;++i)
#pragma unroll
      for (int j=0;j<4;++j)
        acc[i][j] = __builtin_amdgcn_mfma_f32_16x16x32_f16(af[i], bf[j], acc[i][j], 0,0,0);
  }
  const int rm = 4*(lane>>4);  // C/D: col=lane&15, row=4*(lane>>4)+reg (m89-verified)
#pragma unroll
  for (int i=0;i<4;++i) {
#pragma unroll
    for (int r=0;r<4;++r) {
      const int row = mt*128 + wr*64 + i*16 + rm + r;
#pragma unroll
      for (int j=0;j<4;++j) {
        const int col = nt*128 + wc*64 + j*16 + lr;
        const float v = acc[i][j][r] + bias[col];
        if (MODE == 0) {
          Cout[(size_t)row*ldc + col] = v;
        } else {
          if (row < 2528) {
            const int b = row / 79;
            const int t = row - b*79;
            Cout[(size_t)(b*80 + t + 1)*VV + col] = v;  // logits[b, t+1, :]
          }
        }
      }
    }
  }
}

// ---------------- persistent recurrence: encoder 80 + decoder 79 steps -------
// 32 WGs x 128 threads. WG w owns h columns [w*16, w*16+16) for ALL batches;
// its 48x512 Whh slice (r,z,n gate rows) lives in LDS as fp16.
// One grid barrier per step; h is ping-pong buffered (p = t&1).
__global__ __launch_bounds__(128) void seq_recur(
    const float* __restrict__ eWhh, const float* __restrict__ dWhh,
    const float* __restrict__ ebhh, const float* __restrict__ dbhh,
    const float* __restrict__ giE, const float* __restrict__ giD,
    float* __restrict__ h32, _Float16* __restrict__ h16,
    _Float16* __restrict__ eo, _Float16* __restrict__ comb,
    unsigned* __restrict__ bar)
{
  const int w = blockIdx.x;
  const int tid = threadIdx.x;
  const int lane = tid & 63;
  const int wv = tid >> 6;                 // 0..1 -> batch half (bi)
  __shared__ _Float16 whh[48][520];        // +8 halves pad: kill b128 bank conflicts
  __shared__ float hsh[HH];
  __shared__ float sc[SS];
  __shared__ float aw[SS];
  unsigned bphase = 0;

  auto loadW = [&](const float* W){
    for (int i = tid; i < 48*512; i += 128) {
      const int r = i >> 9, k = i & 511;
      const int grow = (r >> 4)*HH + (w<<4) + (r & 15);  // gate*512 + w*16 + jj
      whh[r][k] = (_Float16)W[(size_t)grow*HH + k];
    }
  };
  auto gbar = [&](){
    __syncthreads();
    if (tid == 0) {
      __threadfence();  // release h writes (wb L2)
      __hip_atomic_fetch_add(bar, 1u, __ATOMIC_RELEASE, __HIP_MEMORY_SCOPE_AGENT);
      const unsigned tg = (++bphase)*32u;
      while (__hip_atomic_load(bar, __ATOMIC_RELAXED, __HIP_MEMORY_SCOPE_AGENT) < tg) {
        __builtin_amdgcn_s_sleep(1);
      }
      __threadfence();  // acquire (inv L2)
    }
    __syncthreads();
  };

  const int b  = (wv<<4) + (lane & 15);
  const int jb = 4*(lane>>4);
  const int g8 = (lane>>4)*8;
  const int lr = lane & 15;

  auto gru = [&](const float* gi_t, int gistr, const float* bhh, int p, _Float16* eo_t){
    floatx4 a0 = (floatx4){0.f,0.f,0.f,0.f}, a1 = a0, a2 = a0;
    const _Float16* hb = h16 + (size_t)p*BB*HH + (size_t)b*HH;
#pragma unroll
    for (int kt=0; kt<16; ++kt) {
      const int kof = kt*32 + g8;
      const half8 bf = *(const half8*)(hb + kof);
      const half8 x0 = *(const half8*)(&whh[lr][kof]);
      const half8 x1 = *(const half8*)(&whh[16+lr][kof]);
      const half8 x2 = *(const half8*)(&whh[32+lr][kof]);
      a0 = __builtin_amdgcn_mfma_f32_16x16x32_f16(x0, bf, a0, 0,0,0);
      a1 = __builtin_amdgcn_mfma_f32_16x16x32_f16(x1, bf, a1, 0,0,0);
      a2 = __builtin_amdgcn_mfma_f32_16x16x32_f16(x2, bf, a2, 0,0,0);
    }
    const float* gi = gi_t + (size_t)b*gistr;
    float*    hN   = h32 + (size_t)(1-p)*BB*HH;
    _Float16* hN16 = h16 + (size_t)(1-p)*BB*HH;
    const float* hP = h32 + (size_t)p*BB*HH;
#pragma unroll
    for (int r=0;r<4;++r){
      const int j = (w<<4) + jb + r;
      const float ir = gi[j], iz = gi[HH+j], inn = gi[2*HH+j];
      const float ghr = a0[r] + bhh[j];
      const float ghz = a1[r] + bhh[HH+j];
      const float ghn = a2[r] + bhh[2*HH+j];
      const float rg = 1.f/(1.f + __expf(-(ir+ghr)));
      const float zg = 1.f/(1.f + __expf(-(iz+ghz)));
      const float xx = inn + rg*ghn;
      const float ng = 2.f/(1.f + __expf(-2.f*xx)) - 1.f;   // tanh
      const float hn = (1.f - zg)*ng + zg*hP[(size_t)b*HH + j];
      hN[(size_t)b*HH + j]   = hn;
      hN16[(size_t)b*HH + j] = (_Float16)hn;
      if (eo_t) eo_t[(size_t)b*SS*HH + j] = (_Float16)hn;
    }
  };

  // init h buffer 0 (WG w zeroes batch w's row)
  for (int i = tid; i < HH; i += 128) {
    h32[(size_t)w*HH + i] = 0.f;
    h16[(size_t)w*HH + i] = (_Float16)0.f;
  }
  loadW(eWhh);
  gbar();

  // -------- encoder --------
  for (int t=0; t<SS; ++t) {
    gru(giE + (size_t)t*1536, SS*1536, ebhh, t&1, eo + (size_t)t*HH);
    gbar();
  }

  // -------- decoder --------
  loadW(dWhh);
  __syncthreads();
  for (int t=0; t<TT-1; ++t) {
    const int p = t & 1;   // 80 encoder steps were even, parity continues
    gru(giD + (size_t)t*1536, 79*1536, dbhh, p, nullptr);
    gbar();
    // attention for batch b=w on the NEW h (buffer 1-p)
    const int pn = 1-p;
    const float* hD = h32 + (size_t)pn*BB*HH + (size_t)w*HH;
    for (int i=tid;i<HH;i+=128) hsh[i] = hD[i];
    __syncthreads();
    for (int it=0; it<40; ++it) {
      const int s = wv*40 + it;
      const half8 ev = *(const half8*)(eo + ((size_t)w*SS + s)*HH + lane*8);
      float part = 0.f;
#pragma unroll
      for (int q=0;q<8;++q) part += (float)ev[q]*hsh[lane*8+q];
#pragma unroll
      for (int o=32;o;o>>=1) part += __shfl_xor(part, o);
      if (lane==0) sc[s] = part;
    }
    __syncthreads();
    if (wv==0) {
      const float v0 = sc[lane];
      const float v1 = (lane<16)? sc[64+lane] : -1e30f;
      float m = fmaxf(v0,v1);
#pragma unroll
      for (int o=32;o;o>>=1) m = fmaxf(m, __shfl_xor(m,o));
      const float e0 = __expf(v0-m);
      const float e1 = (lane<16)? __expf(v1-m) : 0.f;
      float ssum = e0+e1;
#pragma unroll
      for (int o=32;o;o>>=1) ssum += __shfl_xor(ssum,o);
      const float inv = 1.f/ssum;
      aw[lane] = e0*inv;
      if (lane<16) aw[64+lane] = e1*inv;
    }
    __syncthreads();
    float c0=0.f,c1=0.f,c2=0.f,c3=0.f;
    const _Float16* ebase = eo + (size_t)w*SS*HH + tid*4;
#pragma unroll 4
    for (int s=0;s<SS;++s){
      const float a = aw[s];
      const half4 hv = *(const half4*)(ebase + (size_t)s*HH);
      c0 += a*(float)hv[0]; c1 += a*(float)hv[1];
      c2 += a*(float)hv[2]; c3 += a*(float)hv[3];
    }
    _Float16* cr = comb + ((size_t)w*79 + t)*1024;
    for (int i=tid;i<HH;i+=128) cr[i] = (_Float16)hsh[i];
    cr[HH + tid*4 + 0] = (_Float16)c0;
    cr[HH + tid*4 + 1] = (_Float16)c1;
    cr[HH + tid*4 + 2] = (_Float16)c2;
    cr[HH + tid*4 + 3] = (_Float16)c3;
  }
  // zero pad rows of combined (2528..2559)
  {
    _Float16* cr = comb + (size_t)(2528 + w)*1024;
    for (int i=tid;i<1024;i+=128) cr[i] = (_Float16)0.f;
  }
}

// ---------------- logits[:,0,:] = 0 ----------------
__global__ __launch_bounds__(256) void zero_t0(float* __restrict__ out)
{
  const int i = blockIdx.x*256 + threadIdx.x;
  if (i < BB*VV) {
    const int b = i / VV, v = i - b*VV;
    out[(size_t)(b*TT)*VV + v] = 0.f;
  }
}

extern "C" void kernel_launch(void* const* d_in, const int* in_sizes, int n_in,
                              void* d_out, int out_size, void* d_ws, size_t ws_size,
                              hipStream_t stream) {
  (void)in_sizes; (void)n_in; (void)out_size; (void)ws_size;
  const int*   src  = (const int*)d_in[0];
  const int*   tgt  = (const int*)d_in[1];
  const float* emb  = (const float*)d_in[2];
  const float* eWih = (const float*)d_in[3];
  const float* eWhh = (const float*)d_in[4];
  const float* ebih = (const float*)d_in[5];
  const float* ebhh = (const float*)d_in[6];
  const float* dWih = (const float*)d_in[7];
  const float* dWhh = (const float*)d_in[8];
  const float* dbih = (const float*)d_in[9];
  const float* dbhh = (const float*)d_in[10];
  const float* outW = (const float*)d_in[11];
  const float* outb = (const float*)d_in[12];
  float* out = (float*)d_out;

  char* p = (char*)d_ws;
  auto alloc = [&](size_t n){ char* r = p; p += (n + 255) & ~(size_t)255; return r; };
  _Float16* xsrc = (_Float16*)alloc((size_t)2560*256*2);
  _Float16* xdec = (_Float16*)alloc((size_t)2560*256*2);
  _Float16* wEh  = (_Float16*)alloc((size_t)1536*256*2);
  _Float16* wDh  = (_Float16*)alloc((size_t)1536*256*2);
  _Float16* oWh  = (_Float16*)alloc((size_t)VV*1024*2);
  float*    giE  = (float*)alloc((size_t)2560*1536*4);
  float*    giD  = (float*)alloc((size_t)2560*1536*4);
  float*    h32  = (float*)alloc((size_t)2*BB*HH*4);
  _Float16* h16  = (_Float16*)alloc((size_t)2*BB*HH*2);
  _Float16* eo   = (_Float16*)alloc((size_t)BB*SS*HH*2);
  _Float16* comb = (_Float16*)alloc((size_t)2560*1024*2);
  unsigned* bar  = (unsigned*)alloc(256);

  hipMemsetAsync(bar, 0, 256, stream);
  embed_gather<<<5120, 256, 0, stream>>>(src, tgt, emb, xsrc, xdec);
  wconv<<<2048, 256, 0, stream>>>(eWih, dWih, outW, wEh, wDh, oWh);
  // gi = x @ Wih^T + bih for all timesteps at once
  mfma_gemm<0><<<dim3(12,20), 256, 0, stream>>>(xsrc, 256, wEh, 256, ebih, giE, 1536, 256);
  mfma_gemm<0><<<dim3(12,20), 256, 0, stream>>>(xdec, 256, wDh, 256, dbih, giD, 1536, 256);
  seq_recur<<<32, 128, 0, stream>>>(eWhh, dWhh, ebhh, dbhh, giE, giD, h32, h16, eo, comb, bar);
  zero_t0<<<4000, 256, 0, stream>>>(out);
  // logits = combined @ out_W^T + out_b, scattered to [b, t+1, :]
  mfma_gemm<1><<<dim3(250,20), 256, 0, stream>>>(comb, 1024, oWh, 1024, outb, out, 0, 1024);
}

// Round 2
// 2535.454 us; speedup vs baseline: 1.1150x; 1.1150x over previous
//
#include <hip/hip_runtime.h>

#define VV 32000
#define EE 256
#define HH 512
#define BB 32
#define SS 80
#define TT 80
// decoder rows = B*(T-1) = 2528, padded to 2560 (20 tiles of 128)

typedef __attribute__((ext_vector_type(8))) _Float16 half8;
typedef __attribute__((ext_vector_type(4))) _Float16 half4;
typedef __attribute__((ext_vector_type(4))) float floatx4;
typedef unsigned long long u64;

__device__ __forceinline__ void gload16(const _Float16* g, _Float16* l) {
  // async global->LDS, 16B per lane; LDS dest is wave-uniform base + lane*16
  __builtin_amdgcn_global_load_lds((const __attribute__((address_space(1))) void*)g,
                                   (__attribute__((address_space(3))) void*)l, 16, 0, 0);
}

__device__ __forceinline__ u64 aload(const u64* p) {
  return __hip_atomic_load(p, __ATOMIC_RELAXED, __HIP_MEMORY_SCOPE_AGENT);
}
__device__ __forceinline__ void astore(u64* p, u64 v) {
  __hip_atomic_store(p, v, __ATOMIC_RELAXED, __HIP_MEMORY_SCOPE_AGENT);
}

// ---------------- embedding gather (fp32 -> fp16 rows) ----------------
__global__ __launch_bounds__(256) void embed_gather(
    const int* __restrict__ src, const int* __restrict__ tgt,
    const float* __restrict__ emb,
    _Float16* __restrict__ xsrc, _Float16* __restrict__ xdec)
{
  const int r = blockIdx.x;
  const int e = threadIdx.x; // EE == 256
  if (r < 2560) {
    const int tok = src[r];                       // r = b*80+s
    xsrc[(size_t)r*EE + e] = (_Float16)emb[(size_t)tok*EE + e];
  } else {
    const int rr = r - 2560;
    if (rr < 2528) {
      const int b = rr / 79, t = rr - b*79;
      const int tok = tgt[b*TT + t];
      xdec[(size_t)rr*EE + e] = (_Float16)emb[(size_t)tok*EE + e];
    } else {
      xdec[(size_t)rr*EE + e] = (_Float16)0.f;    // pad rows 2528..2559
    }
  }
}

// ---------------- weight fp32 -> fp16 conversion ----------------
__global__ __launch_bounds__(256) void wconv(
    const float* __restrict__ we, const float* __restrict__ wd, const float* __restrict__ ow,
    _Float16* __restrict__ weh, _Float16* __restrict__ wdh, _Float16* __restrict__ owh)
{
  const long n1 = 1536L*256;
  const long total = 2*n1 + (long)VV*1024;
  for (long i = (long)blockIdx.x*256 + threadIdx.x; i < total; i += (long)gridDim.x*256) {
    if (i < n1)           weh[i]        = (_Float16)we[i];
    else if (i < 2*n1)    wdh[i-n1]     = (_Float16)wd[i-n1];
    else                  owh[i-2*n1]   = (_Float16)ow[i-2*n1];
  }
}

// ---------------- generic fp16 MFMA GEMM: C(MxN) = A(MxK) * B(NxK)^T + bias ----
// MODE 0: C[row*ldc+col].  MODE 1: seq2seq logits scatter (skip rows>=2528).
template<int MODE>
__global__ __launch_bounds__(256) void mfma_gemm(
    const _Float16* __restrict__ A, int lda,
    const _Float16* __restrict__ Bm, int ldb,
    const float* __restrict__ bias,
    float* __restrict__ Cout, int ldc, int K)
{
  __shared__ _Float16 As[4096];  // 128 x 32
  __shared__ _Float16 Bs[4096];  // 128 x 32
  const int tid = threadIdx.x;
  const int lane = tid & 63;
  const int wv = tid >> 6;
  const int wr = wv >> 1, wc = wv & 1;
  const int mt = blockIdx.y, nt = blockIdx.x;
  floatx4 acc[4][4];
#pragma unroll
  for (int i=0;i<4;++i)
#pragma unroll
    for (int j=0;j<4;++j) acc[i][j] = (floatx4){0.f,0.f,0.f,0.f};
  const int srow = lane >> 2;
  const int scol = (lane & 3) * 8;
  const _Float16* Ab = A + (size_t)(mt*128)*lda;
  const _Float16* Bb = Bm + (size_t)(nt*128)*ldb;
  const int g8 = (lane >> 4) * 8;
  const int lr = lane & 15;
  for (int kb = 0; kb < K; kb += 32) {
    __syncthreads();   // protect LDS from prior iteration's readers
#pragma unroll
    for (int cc = 0; cc < 2; ++cc) {
      const int c = wv*2 + cc;   // 8 chunks of 1KB per 8KB tile
      gload16(Ab + (size_t)(c*16 + srow)*lda + kb + scol, As + c*512);
      gload16(Bb + (size_t)(c*16 + srow)*ldb + kb + scol, Bs + c*512);
    }
    __syncthreads();   // compiler drains vmcnt before barrier
    half8 af[4], bf[4];
#pragma unroll
    for (int i=0;i<4;++i) af[i] = *(const half8*)(As + (wr*64 + i*16 + lr)*32 + g8);
#pragma unroll
    for (int j=0;j<4;++j) bf[j] = *(const half8*)(Bs + (wc*64 + j*16 + lr)*32 + g8);
#pragma unroll
    for (int i=0;i<4;++i)
#pragma unroll
      for (int j=0;j<4;++j)
        acc[i][j] = __builtin_amdgcn_mfma_f32_16x16x32_f16(af[i], bf[j], acc[i][j], 0,0,0);
  }
  const int rm = 4*(lane>>4);  // C/D: col=lane&15, row=4*(lane>>4)+reg (m89-verified)
#pragma unroll
  for (int i=0;i<4;++i) {
#pragma unroll
    for (int r=0;r<4;++r) {
      const int row = mt*128 + wr*64 + i*16 + rm + r;
#pragma unroll
      for (int j=0;j<4;++j) {
        const int col = nt*128 + wc*64 + j*16 + lr;
        const float v = acc[i][j][r] + bias[col];
        if (MODE == 0) {
          Cout[(size_t)row*ldc + col] = v;
        } else {
          if (row < 2528) {
            const int b = row / 79;
            const int t = row - b*79;
            Cout[(size_t)(b*80 + t + 1)*VV + col] = v;  // logits[b, t+1, :]
          }
        }
      }
    }
  }
}

// ---------------- persistent recurrence: encoder 80 + decoder 79 steps -------
// 32 WGs x 128 threads. WG w owns h columns [w*16, w*16+16) for ALL batches;
// its 48x512 Whh slice (r,z,n gate rows) lives in LDS as fp16.
// Cross-WG h exchange goes through agent-scope relaxed atomics (coherence
// point / LLC) -- NO __threadfence, so per-XCD L2 stays warm for gi/eo.
// fp32 h_prev lives in per-thread registers (each thread owns 4 h columns of
// one batch). One grid barrier per step; h ping-pong (p = t&1).
__global__ __launch_bounds__(128) void seq_recur(
    const float* __restrict__ eWhh, const float* __restrict__ dWhh,
    const float* __restrict__ ebhh, const float* __restrict__ dbhh,
    const float* __restrict__ giE, const float* __restrict__ giD,
    _Float16* __restrict__ h16,
    _Float16* __restrict__ eo, _Float16* __restrict__ comb,
    unsigned* __restrict__ bar)
{
  const int w = blockIdx.x;
  const int tid = threadIdx.x;
  const int lane = tid & 63;
  const int wv = tid >> 6;                 // 0..1 -> batch half
  __shared__ _Float16 whh[48][520];        // +8 halves pad: kill b128 bank conflicts
  __shared__ float hsh[HH];
  __shared__ float sc[SS];
  __shared__ float aw[SS];
  unsigned bphase = 0;

  auto loadW = [&](const float* W){
    for (int i = tid; i < 48*512; i += 128) {
      const int r = i >> 9, k = i & 511;
      const int grow = (r >> 4)*HH + (w<<4) + (r & 15);  // gate*512 + w*16 + jj
      whh[r][k] = (_Float16)W[(size_t)grow*HH + k];
    }
  };
  auto gbar = [&](){
    __syncthreads();   // drains vmcnt(0): all waves' atomic stores complete
    if (tid == 0) {
      __hip_atomic_fetch_add(bar, 1u, __ATOMIC_RELEASE, __HIP_MEMORY_SCOPE_AGENT);
      const unsigned tg = (++bphase)*32u;
      while (__hip_atomic_load(bar, __ATOMIC_RELAXED, __HIP_MEMORY_SCOPE_AGENT) < tg) {
        __builtin_amdgcn_s_sleep(1);
      }
      asm volatile("" ::: "memory");
    }
    __syncthreads();
  };

  const int b  = (wv<<4) + (lane & 15);
  const int jb = 4*(lane>>4);
  const int g8 = (lane>>4)*8;
  const int lr = lane & 15;
  float hp[4] = {0.f, 0.f, 0.f, 0.f};     // own fp32 h_prev (batch b, cols j..j+3)

  auto gru = [&](const float* gi_t, int gistr, const float* bhh, int p, _Float16* eo_t){
    floatx4 a0 = (floatx4){0.f,0.f,0.f,0.f}, a1 = a0, a2 = a0;
    const u64* hb = (const u64*)(h16 + (size_t)p*BB*HH + (size_t)b*HH);
#pragma unroll
    for (int kt=0; kt<16; ++kt) {
      const int kof = kt*32 + g8;
      const int qi  = kof >> 2;            // u64 index
      union { u64 q[2]; half8 v; } hu;
      hu.q[0] = aload(hb + qi);
      hu.q[1] = aload(hb + qi + 1);
      const half8 bf = hu.v;
      const half8 x0 = *(const half8*)(&whh[lr][kof]);
      const half8 x1 = *(const half8*)(&whh[16+lr][kof]);
      const half8 x2 = *(const half8*)(&whh[32+lr][kof]);
      a0 = __builtin_amdgcn_mfma_f32_16x16x32_f16(x0, bf, a0, 0,0,0);
      a1 = __builtin_amdgcn_mfma_f32_16x16x32_f16(x1, bf, a1, 0,0,0);
      a2 = __builtin_amdgcn_mfma_f32_16x16x32_f16(x2, bf, a2, 0,0,0);
    }
    const float* gi = gi_t + (size_t)b*gistr;
    union { u64 q; _Float16 h[4]; } hw;
#pragma unroll
    for (int r=0;r<4;++r){
      const int j = (w<<4) + jb + r;
      const float ir = gi[j], iz = gi[HH+j], inn = gi[2*HH+j];
      const float ghr = a0[r] + bhh[j];
      const float ghz = a1[r] + bhh[HH+j];
      const float ghn = a2[r] + bhh[2*HH+j];
      const float rg = 1.f/(1.f + __expf(-(ir+ghr)));
      const float zg = 1.f/(1.f + __expf(-(iz+ghz)));
      const float xx = inn + rg*ghn;
      const float ng = 2.f/(1.f + __expf(-2.f*xx)) - 1.f;   // tanh
      const float hn = (1.f - zg)*ng + zg*hp[r];
      hp[r] = hn;
      hw.h[r] = (_Float16)hn;
    }
    astore((u64*)(h16 + (size_t)(1-p)*BB*HH + (size_t)b*HH + (w<<4) + jb), hw.q);
    if (eo_t) astore((u64*)(eo_t + (size_t)b*SS*HH + (w<<4) + jb), hw.q);
  };

  // init h buffer 0: WG w zeroes batch w's row (128 u64 words = 512 fp16)
  astore((u64*)h16 + (size_t)w*(HH/4) + tid, 0ull);
  loadW(eWhh);
  gbar();

  // -------- encoder --------
  for (int t=0; t<SS; ++t) {
    gru(giE + (size_t)t*1536, SS*1536, ebhh, t&1, eo + (size_t)t*HH);
    gbar();
  }

  // -------- decoder --------
  loadW(dWhh);
  __syncthreads();
  for (int t=0; t<TT-1; ++t) {
    const int p = t & 1;   // 80 encoder steps were even, parity continues
    gru(giD + (size_t)t*1536, 79*1536, dbhh, p, nullptr);
    gbar();
    // attention for batch b=w on the NEW h (buffer 1-p), via coherent h16
    const int pn = 1-p;
    {
      const u64* hd = (const u64*)(h16 + (size_t)pn*BB*HH + (size_t)w*HH);
      union { u64 q; _Float16 h[4]; } hu;
      hu.q = aload(hd + tid);
      hsh[tid*4+0] = (float)hu.h[0];
      hsh[tid*4+1] = (float)hu.h[1];
      hsh[tid*4+2] = (float)hu.h[2];
      hsh[tid*4+3] = (float)hu.h[3];
    }
    __syncthreads();
    for (int it=0; it<40; ++it) {
      const int s = wv*40 + it;
      const half8 ev = *(const half8*)(eo + ((size_t)w*SS + s)*HH + lane*8);
      float part = 0.f;
#pragma unroll
      for (int q=0;q<8;++q) part += (float)ev[q]*hsh[lane*8+q];
#pragma unroll
      for (int o=32;o;o>>=1) part += __shfl_xor(part, o);
      if (lane==0) sc[s] = part;
    }
    __syncthreads();
    if (wv==0) {
      const float v0 = sc[lane];
      const float v1 = (lane<16)? sc[64+lane] : -1e30f;
      float m = fmaxf(v0,v1);
#pragma unroll
      for (int o=32;o;o>>=1) m = fmaxf(m, __shfl_xor(m,o));
      const float e0 = __expf(v0-m);
      const float e1 = (lane<16)? __expf(v1-m) : 0.f;
      float ssum = e0+e1;
#pragma unroll
      for (int o=32;o;o>>=1) ssum += __shfl_xor(ssum,o);
      const float inv = 1.f/ssum;
      aw[lane] = e0*inv;
      if (lane<16) aw[64+lane] = e1*inv;
    }
    __syncthreads();
    float c0=0.f,c1=0.f,c2=0.f,c3=0.f;
    const _Float16* ebase = eo + (size_t)w*SS*HH + tid*4;
#pragma unroll 4
    for (int s=0;s<SS;++s){
      const float a = aw[s];
      const half4 hv = *(const half4*)(ebase + (size_t)s*HH);
      c0 += a*(float)hv[0]; c1 += a*(float)hv[1];
      c2 += a*(float)hv[2]; c3 += a*(float)hv[3];
    }
    _Float16* cr = comb + ((size_t)w*79 + t)*1024;
    for (int i=tid;i<HH;i+=128) cr[i] = (_Float16)hsh[i];
    cr[HH + tid*4 + 0] = (_Float16)c0;
    cr[HH + tid*4 + 1] = (_Float16)c1;
    cr[HH + tid*4 + 2] = (_Float16)c2;
    cr[HH + tid*4 + 3] = (_Float16)c3;
    __syncthreads();   // hsh/aw reused next iteration
  }
  // zero pad rows of combined (2528..2559)
  {
    _Float16* cr = comb + (size_t)(2528 + w)*1024;
    for (int i=tid;i<1024;i+=128) cr[i] = (_Float16)0.f;
  }
}

// ---------------- logits[:,0,:] = 0 ----------------
__global__ __launch_bounds__(256) void zero_t0(float* __restrict__ out)
{
  const int i = blockIdx.x*256 + threadIdx.x;
  if (i < BB*VV) {
    const int b = i / VV, v = i - b*VV;
    out[(size_t)(b*TT)*VV + v] = 0.f;
  }
}

extern "C" void kernel_launch(void* const* d_in, const int* in_sizes, int n_in,
                              void* d_out, int out_size, void* d_ws, size_t ws_size,
                              hipStream_t stream) {
  (void)in_sizes; (void)n_in; (void)out_size; (void)ws_size;
  const int*   src  = (const int*)d_in[0];
  const int*   tgt  = (const int*)d_in[1];
  const float* emb  = (const float*)d_in[2];
  const float* eWih = (const float*)d_in[3];
  const float* eWhh = (const float*)d_in[4];
  const float* ebih = (const float*)d_in[5];
  const float* ebhh = (const float*)d_in[6];
  const float* dWih = (const float*)d_in[7];
  const float* dWhh = (const float*)d_in[8];
  const float* dbih = (const float*)d_in[9];
  const float* dbhh = (const float*)d_in[10];
  const float* outW = (const float*)d_in[11];
  const float* outb = (const float*)d_in[12];
  float* out = (float*)d_out;

  char* p = (char*)d_ws;
  auto alloc = [&](size_t n){ char* r = p; p += (n + 255) & ~(size_t)255; return r; };
  _Float16* xsrc = (_Float16*)alloc((size_t)2560*256*2);
  _Float16* xdec = (_Float16*)alloc((size_t)2560*256*2);
  _Float16* wEh  = (_Float16*)alloc((size_t)1536*256*2);
  _Float16* wDh  = (_Float16*)alloc((size_t)1536*256*2);
  _Float16* oWh  = (_Float16*)alloc((size_t)VV*1024*2);
  float*    giE  = (float*)alloc((size_t)2560*1536*4);
  float*    giD  = (float*)alloc((size_t)2560*1536*4);
  _Float16* h16  = (_Float16*)alloc((size_t)2*BB*HH*2);
  _Float16* eo   = (_Float16*)alloc((size_t)BB*SS*HH*2);
  _Float16* comb = (_Float16*)alloc((size_t)2560*1024*2);
  unsigned* bar  = (unsigned*)alloc(256);

  hipMemsetAsync(bar, 0, 256, stream);
  embed_gather<<<5120, 256, 0, stream>>>(src, tgt, emb, xsrc, xdec);
  wconv<<<2048, 256, 0, stream>>>(eWih, dWih, outW, wEh, wDh, oWh);
  // gi = x @ Wih^T + bih for all timesteps at once
  mfma_gemm<0><<<dim3(12,20), 256, 0, stream>>>(xsrc, 256, wEh, 256, ebih, giE, 1536, 256);
  mfma_gemm<0><<<dim3(12,20), 256, 0, stream>>>(xdec, 256, wDh, 256, dbih, giD, 1536, 256);
  seq_recur<<<32, 128, 0, stream>>>(eWhh, dWhh, ebhh, dbhh, giE, giD, h16, eo, comb, bar);
  zero_t0<<<4000, 256, 0, stream>>>(out);
  // logits = combined @ out_W^T + out_b, scattered to [b, t+1, :]
  mfma_gemm<1><<<dim3(250,20), 256, 0, stream>>>(comb, 1024, oWh, 1024, outb, out, 0, 1024);
}